// Round 2
// baseline (249.455 us; speedup 1.0000x reference)
//
#include <hip/hip_runtime.h>
#include <stdint.h>

// SelfAttention: B=4, S=2048, D=1024, causal, single head of dim 1024.
// R7: 256x256 core restructured to the exact m201 template: 2 K-tiles per
// loop iteration (8 phases), COMPILE-TIME buffer indices, B0 held in regs
// (24 ds_read_b128/wave/tile), 1 half-tile stage per phase, vmcnt(4) only
// at ph3/ph7. pv keeps the 128^2 core.

typedef unsigned short u16;
typedef __attribute__((ext_vector_type(8))) short shortx8;  // 8 bf16 (4 VGPRs)
typedef __attribute__((ext_vector_type(4))) float floatx4;

static constexpr int BB = 4;
static constexpr int SS = 2048;
static constexpr int DD = 1024;

__device__ __forceinline__ u16 f2bf(float f) {
  union { float f; uint32_t u; } c; c.f = f;
  uint32_t u = c.u;
  return (u16)((u + 0x7fffu + ((u >> 16) & 1u)) >> 16);  // RNE
}

__device__ __forceinline__ float bfhi2f(uint32_t u) {  // high 16 bits as bf16
  union { uint32_t u; float f; } c; c.u = u & 0xffff0000u; return c.f;
}
__device__ __forceinline__ float bflo2f(uint32_t u) {  // low 16 bits as bf16
  union { uint32_t u; float f; } c; c.u = u << 16; return c.f;
}

#define GLOAD_LDS16(g_, l_)                                                             \
  __builtin_amdgcn_global_load_lds((const __attribute__((address_space(1))) void*)(g_), \
                                   (__attribute__((address_space(3))) void*)(l_), 16, 0, 0)

// ---------------------------------------------------------------------------
// 128x128 C-tile GEMM core (2-barrier structure) -- kept for pv_gemm only.
// ---------------------------------------------------------------------------
__device__ __forceinline__ void gemm_core_128(
    const u16* __restrict__ A, const u16* __restrict__ Bt,
    int lda, int ldb, int m0, int n0, int kend, floatx4 acc[4][4])
{
  __shared__ u16 lA[128 * 64];
  __shared__ u16 lB[128 * 64];
  const int t = threadIdx.x;
  const int w = t >> 6, l = t & 63;
  const int wm = w >> 1, wn = w & 1;
  const int sr = l >> 3;
  const int scq = ((l & 7) ^ (l >> 3)) * 8;

#pragma unroll
  for (int i = 0; i < 4; ++i)
#pragma unroll
    for (int j = 0; j < 4; ++j)
      acc[i][j] = (floatx4){0.f, 0.f, 0.f, 0.f};

  const u16* Ab = A + (size_t)m0 * lda;
  const u16* Bb = Bt + (size_t)n0 * ldb;

  for (int k0 = 0; k0 < kend; k0 += 64) {
#pragma unroll
    for (int i = 0; i < 4; ++i) {
      const int row = w * 32 + i * 8;
      GLOAD_LDS16(Ab + (size_t)(row + sr) * lda + k0 + scq, &lA[row * 64]);
      GLOAD_LDS16(Bb + (size_t)(row + sr) * ldb + k0 + scq, &lB[row * 64]);
    }
    __syncthreads();

#pragma unroll
    for (int ks = 0; ks < 2; ++ks) {
      const int ca = ((ks * 4 + (l >> 4)) ^ (l & 7)) * 8;
      shortx8 af[4], bf[4];
#pragma unroll
      for (int i = 0; i < 4; ++i)
        af[i] = *(const shortx8*)&lA[(wm * 64 + i * 16 + (l & 15)) * 64 + ca];
#pragma unroll
      for (int i = 0; i < 4; ++i)
        bf[i] = *(const shortx8*)&lB[(wn * 64 + i * 16 + (l & 15)) * 64 + ca];
#pragma unroll
      for (int i = 0; i < 4; ++i)
#pragma unroll
        for (int j = 0; j < 4; ++j)
          acc[i][j] = __builtin_amdgcn_mfma_f32_16x16x32_bf16(af[i], bf[j], acc[i][j], 0, 0, 0);
    }
    __syncthreads();
  }
}

// ---------------------------------------------------------------------------
// 256x256 C-tile, BK=64, 8 waves (2Mx4N), m201-style 8-phase iteration over
// 2 K-tiles with compile-time double-buffer indices.
// LDS sm[2][2][256*64] bf16 (128 KiB), chunk-XOR swizzle (phys chunk =
// logical ^ (row&7)); staged linearly via pre-swizzled global source.
// Per tile (4 phases): ph+0 loads A0,B0 -> Q(0,0); ph+1 loads B1 -> Q(0,1);
// ph+2 loads A1 (af overwritten) -> Q(1,1); ph+3 NO loads -> Q(1,0) (af,bf0
// held in regs). 24 ds_read_b128 / wave / K-tile.
// Stage schedule (iteration i computes tiles t0=2i in buf0, t0+1 in buf1):
//   ph0: buf1.A1<-t0+1 | ph1: buf0.B0<-t0+2 | ph2: buf0.A0<-t0+2
//   ph3: buf0.B1<-t0+2, vmcnt(4) | ph4: buf0.A1<-t0+2 | ph5: buf1.B0<-t0+3
//   ph6: buf1.A0<-t0+3 | ph7: buf1.B1<-t0+3, vmcnt(4)
// Every stage issues >=1 phase after its slot's last LDS read and completes
// >=3 phases before first use (vmcnt(4) leaves exactly the 2 newest stages
// in flight). Never vmcnt(0) in the loop. kend % 128 == 0 required.
// ---------------------------------------------------------------------------
#define LOAD_AF(buf_, mh_)                                                               \
  _Pragma("unroll")                                                                      \
  for (int mi = 0; mi < 4; ++mi)                                                         \
    _Pragma("unroll")                                                                    \
    for (int kk = 0; kk < 2; ++kk)                                                       \
      af[mi][kk] = *(const shortx8*)&sm[buf_][0][((mh_) * 128 + wr * 64 + mi * 16 + fr) * 64 + \
                                                 (((kk * 4 + fq) ^ (l & 7)) * 8)];

#define LOAD_BF(dst_, buf_, nh_)                                                         \
  _Pragma("unroll")                                                                      \
  for (int ni = 0; ni < 2; ++ni)                                                         \
    _Pragma("unroll")                                                                    \
    for (int kk = 0; kk < 2; ++kk)                                                       \
      dst_[ni][kk] = *(const shortx8*)&sm[buf_][1][((nh_) * 128 + wc * 32 + ni * 16 + fr) * 64 + \
                                                   (((kk * 4 + fq) ^ (l & 7)) * 8)];

#define MFMA_QUAD(mh_, nh_, b_)                                                          \
  do {                                                                                   \
    __builtin_amdgcn_s_setprio(1);                                                       \
    _Pragma("unroll")                                                                    \
    for (int mi = 0; mi < 4; ++mi)                                                       \
      _Pragma("unroll")                                                                  \
      for (int ni = 0; ni < 2; ++ni)                                                     \
        _Pragma("unroll")                                                                \
        for (int kk = 0; kk < 2; ++kk)                                                   \
          acc[mh_][nh_][mi][ni] = __builtin_amdgcn_mfma_f32_16x16x32_bf16(               \
              af[mi][kk], b_[ni][kk], acc[mh_][nh_][mi][ni], 0, 0, 0);                   \
    __builtin_amdgcn_s_setprio(0);                                                       \
  } while (0)

#define STAGE_A(buf_, half_, k_)                                                         \
  do {                                                                                   \
    _Pragma("unroll")                                                                    \
    for (int j = 0; j < 2; ++j) {                                                        \
      const int row0 = (half_) * 128 + wv * 16 + j * 8;                                  \
      GLOAD_LDS16(Ab + (size_t)(row0 + sr) * lda + (k_) + scq, &sm[buf_][0][row0 * 64]); \
    }                                                                                    \
  } while (0)

#define STAGE_B(buf_, half_, k_)                                                         \
  do {                                                                                   \
    _Pragma("unroll")                                                                    \
    for (int j = 0; j < 2; ++j) {                                                        \
      const int row0 = (half_) * 128 + wv * 16 + j * 8;                                  \
      GLOAD_LDS16(Bb + (size_t)(row0 + sr) * ldb + (k_) + scq, &sm[buf_][1][row0 * 64]); \
    }                                                                                    \
  } while (0)

#define PH_SYNC_MFMA(mh_, nh_, b_)                                                       \
  __builtin_amdgcn_s_barrier();                                                          \
  asm volatile("s_waitcnt lgkmcnt(0)" ::: "memory");                                     \
  MFMA_QUAD(mh_, nh_, b_);                                                               \
  __builtin_amdgcn_s_barrier();

__device__ __forceinline__ void gemm_core_256(
    const u16* __restrict__ A, const u16* __restrict__ Bt,
    int lda, int ldb, int m0, int n0, int kend,
    floatx4 (&acc)[2][2][4][2])
{
  __shared__ u16 sm[2][2][256 * 64];  // 128 KiB
  const int t = threadIdx.x;          // 0..511
  const int wv = t >> 6, l = t & 63;
  const int wr = wv >> 2, wc = wv & 3;       // wave grid 2x4 within a quadrant
  const int fr = l & 15, fq = l >> 4;        // frag row / k-subchunk
  const int sr = l >> 3;                     // staging row within 8-row group
  const int scq = ((l & 7) ^ sr) * 8;        // pre-swizzled SOURCE chunk (elems)

#pragma unroll
  for (int a = 0; a < 2; ++a)
#pragma unroll
    for (int bq = 0; bq < 2; ++bq)
#pragma unroll
      for (int mi = 0; mi < 4; ++mi)
#pragma unroll
        for (int ni = 0; ni < 2; ++ni)
          acc[a][bq][mi][ni] = (floatx4){0.f, 0.f, 0.f, 0.f};

  const u16* Ab = A + (size_t)m0 * lda;
  const u16* Bb = Bt + (size_t)n0 * ldb;
  const int T = kend >> 6;     // even, >= 2
  const int NI = T >> 1;

  // prologue: tile0 all 4 halves -> buf0; tile1's B0,A0,B1 -> buf1.
  // (buf1.A1 is staged in iter0 ph0, matching steady state.)
  STAGE_A(0, 0, 0); STAGE_A(0, 1, 0);
  STAGE_B(0, 0, 0); STAGE_B(0, 1, 0);
  STAGE_B(1, 0, 64);
  STAGE_A(1, 0, 64);
  STAGE_B(1, 1, 64);
  asm volatile("s_waitcnt vmcnt(6)" ::: "memory");  // buf0 resident
  __builtin_amdgcn_s_barrier();

  shortx8 af[4][2], bf0[2][2], bf1[2][2];

  for (int it = 0; it < NI; ++it) {
    const int t0 = it * 2;
    const int k1 = (t0 + 1) * 64;                              // always valid
    const int kA = ((t0 + 2 < T) ? t0 + 2 : T - 1) * 64;       // clamped: tail
    const int kB = ((t0 + 3 < T) ? t0 + 3 : T - 1) * 64;       //  garbage lands
                                                               //  in dead slots
    // ======== K-tile t0 : buf0 ========
    // ph0: Q(0,0)
    LOAD_AF(0, 0); LOAD_BF(bf0, 0, 0);
    STAGE_A(1, 1, k1);
    asm volatile("s_waitcnt lgkmcnt(8)" ::: "memory");
    PH_SYNC_MFMA(0, 0, bf0);

    // ph1: Q(0,1), af(A0) held
    LOAD_BF(bf1, 0, 1);
    STAGE_B(0, 0, kA);
    PH_SYNC_MFMA(0, 1, bf1);

    // ph2: Q(1,1), bf1 held, af overwritten with A1
    LOAD_AF(0, 1);
    STAGE_A(0, 0, kA);
    PH_SYNC_MFMA(1, 1, bf1);

    // ph3: Q(1,0), pure MFMA (af=A1, bf0=B0 held)
    STAGE_B(0, 1, kA);
    __builtin_amdgcn_s_barrier();
    MFMA_QUAD(1, 0, bf0);
    asm volatile("s_waitcnt vmcnt(4)" ::: "memory");  // buf1 fully resident
    __builtin_amdgcn_s_barrier();

    // ======== K-tile t0+1 : buf1 ========
    // ph4: Q(0,0)
    LOAD_AF(1, 0); LOAD_BF(bf0, 1, 0);
    STAGE_A(0, 1, kA);
    asm volatile("s_waitcnt lgkmcnt(8)" ::: "memory");
    PH_SYNC_MFMA(0, 0, bf0);

    // ph5: Q(0,1)
    LOAD_BF(bf1, 1, 1);
    STAGE_B(1, 0, kB);
    PH_SYNC_MFMA(0, 1, bf1);

    // ph6: Q(1,1)
    LOAD_AF(1, 1);
    STAGE_A(1, 0, kB);
    PH_SYNC_MFMA(1, 1, bf1);

    // ph7: Q(1,0), pure MFMA
    STAGE_B(1, 1, kB);
    __builtin_amdgcn_s_barrier();
    MFMA_QUAD(1, 0, bf0);
    asm volatile("s_waitcnt vmcnt(4)" ::: "memory");  // buf0 (next) resident
    __builtin_amdgcn_s_barrier();
  }
  asm volatile("s_waitcnt vmcnt(0)" ::: "memory");  // drain tail garbage stages
}

// ---- kernel 0: prep = x_convert (blocks 0..8191) + wt_build (blocks 8192..8959) ----
__global__ __launch_bounds__(256) void prep(const float* __restrict__ x,
                                            const float* __restrict__ WQ,
                                            const float* __restrict__ WK,
                                            const float* __restrict__ WV,
                                            u16* __restrict__ xb,
                                            u16* __restrict__ Wt) {
  __shared__ float tile[64][65];
  const int bid = blockIdx.x;
  const int t = threadIdx.x;
  if (bid < 8192) {
    const size_t i = (size_t)bid * 256 + t;
    float4 v = ((const float4*)x)[i];
    ushort4 o;
    o.x = f2bf(v.x); o.y = f2bf(v.y); o.z = f2bf(v.z); o.w = f2bf(v.w);
    ((ushort4*)xb)[i] = o;
    return;
  }
  const int r = bid - 8192;
  const int wsel = r >> 8;
  const int rr = r & 255;
  const int k0 = (rr >> 4) * 64, n0 = (rr & 15) * 64;
  const float* W = wsel == 0 ? WQ : (wsel == 1 ? WK : WV);
  const int tx = t & 63, ty = t >> 6;
#pragma unroll
  for (int i = 0; i < 16; ++i)
    tile[ty + i * 4][tx] = W[(size_t)(k0 + ty + i * 4) * DD + n0 + tx];
  __syncthreads();
  u16* dst = Wt + (size_t)wsel * DD * DD;
#pragma unroll
  for (int i = 0; i < 16; ++i)
    dst[(size_t)(n0 + ty + i * 4) * DD + k0 + tx] = f2bf(tile[tx][ty + i * 4]);
}

// ---- kernel 1: fused QKV projection, M=8192 N=3072 K=1024, 256^2 tiles.
//      Q,K row-major bf16; V written TRANSPOSED into Vt[b][d][s]. ----
__global__ __launch_bounds__(512, 2) void qkv_gemm(const u16* __restrict__ x,
                                                   const u16* __restrict__ Wt,
                                                   u16* __restrict__ Q,
                                                   u16* __restrict__ K,
                                                   u16* __restrict__ Vt) {
  const int m0 = blockIdx.x * 256;
  const int n0t = blockIdx.y * 256;
  floatx4 acc[2][2][4][2];
  gemm_core_256(x, Wt, DD, DD, m0, n0t, DD, acc);

  const int t = threadIdx.x, wv = t >> 6, l = t & 63;
  const int wr = wv >> 2, wc = wv & 3;
  const int fr = l & 15, fq = l >> 4;

  if (n0t >= 2048) {  // V tile: transposed write, 4 contiguous s per frag
    const int bb = m0 >> 11;
    u16* vt = Vt + (size_t)bb * DD * SS;
    const int sb = m0 & 2047;
#pragma unroll
    for (int mh = 0; mh < 2; ++mh)
#pragma unroll
      for (int nh = 0; nh < 2; ++nh)
#pragma unroll
        for (int mi = 0; mi < 4; ++mi)
#pragma unroll
          for (int ni = 0; ni < 2; ++ni) {
            const int d = (n0t - 2048) + nh * 128 + wc * 32 + ni * 16 + fr;
            const int s = sb + mh * 128 + wr * 64 + mi * 16 + fq * 4;
            ushort4 o4;
            o4.x = f2bf(acc[mh][nh][mi][ni][0]);
            o4.y = f2bf(acc[mh][nh][mi][ni][1]);
            o4.z = f2bf(acc[mh][nh][mi][ni][2]);
            o4.w = f2bf(acc[mh][nh][mi][ni][3]);
            *(ushort4*)(vt + (size_t)d * SS + s) = o4;
          }
    return;
  }

  u16* out = (n0t < 1024) ? Q : K;
  const int n0 = n0t & 1023;
#pragma unroll
  for (int mh = 0; mh < 2; ++mh)
#pragma unroll
    for (int nh = 0; nh < 2; ++nh)
#pragma unroll
      for (int mi = 0; mi < 4; ++mi)
#pragma unroll
        for (int ni = 0; ni < 2; ++ni)
#pragma unroll
          for (int r = 0; r < 4; ++r) {
            const int m = m0 + mh * 128 + wr * 64 + mi * 16 + fq * 4 + r;
            const int n = n0 + nh * 128 + wc * 32 + ni * 16 + fr;
            out[(size_t)m * DD + n] = f2bf(acc[mh][nh][mi][ni][r]);
          }
}

// ---- kernel 2: Scb = bf16(Q K^T / 32), lower-tri 256^2 blocks,
//      triangular-packed grid: blockIdx.x in [0,36) decodes to (mb,nb) ----
__global__ __launch_bounds__(512, 2) void scores_gemm(const u16* __restrict__ Q,
                                                      const u16* __restrict__ Kt,
                                                      u16* __restrict__ Scb) {
  const int b = blockIdx.z;
  const int tcode = blockIdx.x;  // 0..35
  int mb = (int)((sqrtf(8.0f * (float)tcode + 1.0f) - 1.0f) * 0.5f);
  while ((mb + 1) * (mb + 2) / 2 <= tcode) ++mb;
  while (mb * (mb + 1) / 2 > tcode) --mb;
  const int nb = tcode - mb * (mb + 1) / 2;
  const int m0 = mb * 256, n0 = nb * 256;

  floatx4 acc[2][2][4][2];
  gemm_core_256(Q + (size_t)b * SS * DD, Kt + (size_t)b * SS * DD, DD, DD, m0, n0, DD, acc);

  u16* out = Scb + (size_t)b * SS * SS;
  const int t = threadIdx.x, wv = t >> 6, l = t & 63;
  const int wr = wv >> 2, wc = wv & 3;
  const int fr = l & 15, fq = l >> 4;
#pragma unroll
  for (int mh = 0; mh < 2; ++mh)
#pragma unroll
    for (int nh = 0; nh < 2; ++nh)
#pragma unroll
      for (int mi = 0; mi < 4; ++mi)
#pragma unroll
        for (int ni = 0; ni < 2; ++ni)
#pragma unroll
          for (int r = 0; r < 4; ++r) {
            const int m = m0 + mh * 128 + wr * 64 + mi * 16 + fq * 4 + r;
            const int n = n0 + nh * 128 + wc * 32 + ni * 16 + fr;
            out[(size_t)m * SS + n] = f2bf(acc[mh][nh][mi][ni][r] * 0.03125f);
          }
}

// ---- kernel 3: causal row softmax, one WAVE per row, register-cached ----
__global__ __launch_bounds__(256) void softmax_causal(const u16* __restrict__ Scb,
                                                      u16* __restrict__ P) {
  const int row = blockIdx.x * 4 + (threadIdx.x >> 6);
  const int l = threadIdx.x & 63;
  const int b = row >> 11, i = row & 2047;
  const u16* s = Scb + (size_t)b * SS * SS + (size_t)i * SS;
  u16* p = P + (size_t)b * SS * SS + (size_t)i * SS;
  const int n = i + 1;
  const int jend = (i + 128) & ~127;
  const int nc = (jend + 511) >> 9;

  float v[4][8];
  float mx = -INFINITY;
#pragma unroll
  for (int c = 0; c < 4; ++c) {
    if (c < nc) {
      const int col = c * 512 + l * 8;
      uint4 raw = *(const uint4*)(s + col);
      v[c][0] = bflo2f(raw.x); v[c][1] = bfhi2f(raw.x);
      v[c][2] = bflo2f(raw.y); v[c][3] = bfhi2f(raw.y);
      v[c][4] = bflo2f(raw.z); v[c][5] = bfhi2f(raw.z);
      v[c][6] = bflo2f(raw.w); v[c][7] = bfhi2f(raw.w);
#pragma unroll
      for (int e = 0; e < 8; ++e) {
        v[c][e] = (col + e < n) ? v[c][e] : -INFINITY;
        mx = fmaxf(mx, v[c][e]);
      }
    }
  }
#pragma unroll
  for (int o = 32; o > 0; o >>= 1) mx = fmaxf(mx, __shfl_xor(mx, o, 64));

  float sum = 0.f;
#pragma unroll
  for (int c = 0; c < 4; ++c) {
    if (c < nc) {
#pragma unroll
      for (int e = 0; e < 8; ++e) {
        v[c][e] = __expf(v[c][e] - mx);
        sum += v[c][e];
      }
    }
  }
#pragma unroll
  for (int o = 32; o > 0; o >>= 1) sum += __shfl_xor(sum, o, 64);
  const float inv = 1.0f / sum;

#pragma unroll
  for (int c = 0; c < 4; ++c) {
    if (c < nc) {
      const int col = c * 512 + l * 8;
      if (col < jend) {
        uint4 o4;
        o4.x = (uint32_t)f2bf(v[c][0] * inv) | ((uint32_t)f2bf(v[c][1] * inv) << 16);
        o4.y = (uint32_t)f2bf(v[c][2] * inv) | ((uint32_t)f2bf(v[c][3] * inv) << 16);
        o4.z = (uint32_t)f2bf(v[c][4] * inv) | ((uint32_t)f2bf(v[c][5] * inv) << 16);
        o4.w = (uint32_t)f2bf(v[c][6] * inv) | ((uint32_t)f2bf(v[c][7] * inv) << 16);
        *(uint4*)(p + col) = o4;
      }
    }
  }
}

// ---- kernel 4: O = P V (causal K-range), fp32 out; longest blocks first ----
__global__ __launch_bounds__(256, 2) void pv_gemm(const u16* __restrict__ P,
                                                  const u16* __restrict__ Vt,
                                                  float* __restrict__ out) {
  const int b = blockIdx.z;
  const int mb = 15 - blockIdx.y;
  const int m0 = mb * 128, n0 = blockIdx.x * 128;
  floatx4 acc[4][4];
  gemm_core_128(P + (size_t)b * SS * SS, Vt + (size_t)b * DD * SS, SS, SS, m0, n0, m0 + 128, acc);

  float* o = out + (size_t)b * SS * DD;
  const int t = threadIdx.x, w = t >> 6, l = t & 63;
  const int wm = w >> 1, wn = w & 1;
#pragma unroll
  for (int i = 0; i < 4; ++i)
#pragma unroll
    for (int j = 0; j < 4; ++j)
#pragma unroll
      for (int r = 0; r < 4; ++r) {
        const int m = m0 + wm * 64 + i * 16 + (l >> 4) * 4 + r;
        const int n = n0 + wn * 64 + j * 16 + (l & 15);
        o[(size_t)m * DD + n] = acc[i][j][r];
      }
}

extern "C" void kernel_launch(void* const* d_in, const int* in_sizes, int n_in,
                              void* d_out, int out_size, void* d_ws, size_t ws_size,
                              hipStream_t stream) {
  const float* x  = (const float*)d_in[0];
  const float* WQ = (const float*)d_in[1];
  const float* WK = (const float*)d_in[2];
  const float* WV = (const float*)d_in[3];
  float* out = (float*)d_out;

  // workspace carve (bytes): Wt 6M | xb 16M | Q 16M | K 16M | Vt 16M | P 32M | Scb 32M
  char* ws = (char*)d_ws;
  const size_t WT_OFF = 0;
  const size_t XB_OFF = WT_OFF + (size_t)3072 * 1024 * 2;
  const size_t Q_OFF  = XB_OFF + (size_t)BB * SS * DD * 2;
  const size_t K_OFF  = Q_OFF + (size_t)BB * SS * DD * 2;
  const size_t VT_OFF = K_OFF + (size_t)BB * SS * DD * 2;
  const size_t P_OFF  = VT_OFF + (size_t)BB * SS * DD * 2;
  const size_t SC_OFF = P_OFF + (size_t)BB * SS * SS * 2;
  u16* Wt  = (u16*)(ws + WT_OFF);
  u16* xb  = (u16*)(ws + XB_OFF);
  u16* Q   = (u16*)(ws + Q_OFF);
  u16* Kb  = (u16*)(ws + K_OFF);
  u16* Vt  = (u16*)(ws + VT_OFF);
  u16* P   = (u16*)(ws + P_OFF);
  u16* Scb = (u16*)(ws + SC_OFF);

  hipLaunchKernelGGL(prep, dim3(8960), dim3(256), 0, stream, x, WQ, WK, WV, xb, Wt);
  hipLaunchKernelGGL(qkv_gemm, dim3(32, 12), dim3(512), 0, stream, xb, Wt, Q, Kb, Vt);
  hipLaunchKernelGGL(scores_gemm, dim3(36, 1, 4), dim3(512), 0, stream, Q, Kb, Scb);
  hipLaunchKernelGGL(softmax_causal, dim3(2048), dim3(256), 0, stream, Scb, P);
  hipLaunchKernelGGL(pv_gemm, dim3(8, 16, 4), dim3(256), 0, stream, P, Vt, out);
}

// Round 3
// 231.388 us; speedup vs baseline: 1.0781x; 1.0781x over previous
//
#include <hip/hip_runtime.h>
#include <stdint.h>

// SelfAttention: B=4, S=2048, D=1024, causal, single head of dim 1024.
// R8: revert to the proven R5 128x128 core everywhere (888 TF; two 256^2
// 8-phase attempts serialized LDS vs MFMA windows and regressed).
// New: pv long/short co-residency pairing via stride-256 dispatch permutation
// (CU c gets blocks c and c+256 under breadth-first dispatch; pair work sums
// to a uniform 17 units). launch_bounds min-waves 2->3 on GEMMs.

typedef unsigned short u16;
typedef __attribute__((ext_vector_type(8))) short shortx8;  // 8 bf16 (4 VGPRs)
typedef __attribute__((ext_vector_type(4))) float floatx4;

static constexpr int BB = 4;
static constexpr int SS = 2048;
static constexpr int DD = 1024;

__device__ __forceinline__ u16 f2bf(float f) {
  union { float f; uint32_t u; } c; c.f = f;
  uint32_t u = c.u;
  return (u16)((u + 0x7fffu + ((u >> 16) & 1u)) >> 16);  // RNE
}

__device__ __forceinline__ float bfhi2f(uint32_t u) {  // high 16 bits as bf16
  union { uint32_t u; float f; } c; c.u = u & 0xffff0000u; return c.f;
}
__device__ __forceinline__ float bflo2f(uint32_t u) {  // low 16 bits as bf16
  union { uint32_t u; float f; } c; c.u = u << 16; return c.f;
}

#define GLOAD_LDS16(g, l)                                                              \
  __builtin_amdgcn_global_load_lds((const __attribute__((address_space(1))) void*)(g), \
                                   (__attribute__((address_space(3))) void*)(l), 16, 0, 0)

// 128x128 C-tile GEMM core, BK=64, XOR-swizzled LDS:
//   logical 16B chunk c (0..7) of row r lives at physical chunk c ^ (r & 7).
//   A  [M][lda] bf16 row-major rows m0.., Bt [N][ldb] rows n0.. (B^T).
//   acc[4][4] per-wave 4x4 grid of 16x16 fp32 tiles; waves 2x2. kend % 64 == 0.
__device__ __forceinline__ void gemm_core_128(
    const u16* __restrict__ A, const u16* __restrict__ Bt,
    int lda, int ldb, int m0, int n0, int kend, floatx4 acc[4][4])
{
  __shared__ u16 lA[128 * 64];  // [row][64], physical chunks swizzled
  __shared__ u16 lB[128 * 64];
  const int t = threadIdx.x;
  const int w = t >> 6, l = t & 63;
  const int wm = w >> 1, wn = w & 1;
  const int sr = l >> 3;                          // staging row within 8-row group
  const int scq = ((l & 7) ^ (l >> 3)) * 8;       // swizzled SOURCE chunk (elems)

#pragma unroll
  for (int i = 0; i < 4; ++i)
#pragma unroll
    for (int j = 0; j < 4; ++j)
      acc[i][j] = (floatx4){0.f, 0.f, 0.f, 0.f};

  const u16* Ab = A + (size_t)m0 * lda;
  const u16* Bb = Bt + (size_t)n0 * ldb;

  for (int k0 = 0; k0 < kend; k0 += 64) {
    // stage A/B 128x64 tiles: each wave 4 groups of 8 rows per matrix.
#pragma unroll
    for (int i = 0; i < 4; ++i) {
      const int row = w * 32 + i * 8;
      GLOAD_LDS16(Ab + (size_t)(row + sr) * lda + k0 + scq, &lA[row * 64]);
      GLOAD_LDS16(Bb + (size_t)(row + sr) * ldb + k0 + scq, &lB[row * 64]);
    }
    __syncthreads();  // drains vmcnt before barrier -> LDS visible

#pragma unroll
    for (int ks = 0; ks < 2; ++ks) {
      // fragment row = base + (l&15) -> row&7 = l&7; logical chunk q = ks*4 + l/16
      const int ca = ((ks * 4 + (l >> 4)) ^ (l & 7)) * 8;  // physical chunk (elems)
      shortx8 af[4], bf[4];
#pragma unroll
      for (int i = 0; i < 4; ++i)
        af[i] = *(const shortx8*)&lA[(wm * 64 + i * 16 + (l & 15)) * 64 + ca];
#pragma unroll
      for (int i = 0; i < 4; ++i)
        bf[i] = *(const shortx8*)&lB[(wn * 64 + i * 16 + (l & 15)) * 64 + ca];
#pragma unroll
      for (int i = 0; i < 4; ++i)
#pragma unroll
        for (int j = 0; j < 4; ++j)
          acc[i][j] = __builtin_amdgcn_mfma_f32_16x16x32_bf16(af[i], bf[j], acc[i][j], 0, 0, 0);
    }
    __syncthreads();  // protect LDS before next stage
  }
}

// ---- kernel 0: prep = x_convert (blocks 0..8191) + wt_build (blocks 8192..8959) ----
__global__ __launch_bounds__(256) void prep(const float* __restrict__ x,
                                            const float* __restrict__ WQ,
                                            const float* __restrict__ WK,
                                            const float* __restrict__ WV,
                                            u16* __restrict__ xb,
                                            u16* __restrict__ Wt) {
  __shared__ float tile[64][65];
  const int bid = blockIdx.x;
  const int t = threadIdx.x;
  if (bid < 8192) {  // xb = bf16(x), float4-vectorized
    const size_t i = (size_t)bid * 256 + t;
    float4 v = ((const float4*)x)[i];
    ushort4 o;
    o.x = f2bf(v.x); o.y = f2bf(v.y); o.z = f2bf(v.z); o.w = f2bf(v.w);
    ((ushort4*)xb)[i] = o;
    return;
  }
  // Wt[n][k] = bf16(W[k][n]), 64x64 tiles through LDS
  const int r = bid - 8192;      // 0..767
  const int wsel = r >> 8;       // 0..2
  const int rr = r & 255;
  const int k0 = (rr >> 4) * 64, n0 = (rr & 15) * 64;
  const float* W = wsel == 0 ? WQ : (wsel == 1 ? WK : WV);
  const int tx = t & 63, ty = t >> 6;
#pragma unroll
  for (int i = 0; i < 16; ++i)
    tile[ty + i * 4][tx] = W[(size_t)(k0 + ty + i * 4) * DD + n0 + tx];
  __syncthreads();
  u16* dst = Wt + (size_t)wsel * DD * DD;
#pragma unroll
  for (int i = 0; i < 16; ++i)
    dst[(size_t)(n0 + ty + i * 4) * DD + k0 + tx] = f2bf(tile[tx][ty + i * 4]);
}

// ---- kernel 1: fused QKV projection, M=8192 N=3072 K=1024.
//      Q,K written row-major bf16; V written TRANSPOSED into Vt[b][d][s]. ----
__global__ __launch_bounds__(256, 3) void qkv_gemm(const u16* __restrict__ x,
                                                   const u16* __restrict__ Wt,
                                                   u16* __restrict__ Q,
                                                   u16* __restrict__ K,
                                                   u16* __restrict__ Vt) {
  const int m0 = blockIdx.x * 128;
  const int n0t = blockIdx.y * 128;
  floatx4 acc[4][4];
  gemm_core_128(x, Wt, DD, DD, m0, n0t, DD, acc);

  const int t = threadIdx.x, w = t >> 6, l = t & 63;
  const int wm = w >> 1, wn = w & 1;

  if (n0t >= 2048) {  // V tile: write transposed. Each lane: 4 contiguous s per (i,j).
    const int bb = m0 >> 11;
    const int s0 = (m0 & 2047) + wm * 64 + (l >> 4) * 4;
    u16* vt = Vt + (size_t)bb * DD * SS;
#pragma unroll
    for (int i = 0; i < 4; ++i)
#pragma unroll
      for (int j = 0; j < 4; ++j) {
        const int n = (n0t - 2048) + wn * 64 + j * 16 + (l & 15);
        const int s = s0 + i * 16;
        ushort4 o4;
        o4.x = f2bf(acc[i][j][0]);
        o4.y = f2bf(acc[i][j][1]);
        o4.z = f2bf(acc[i][j][2]);
        o4.w = f2bf(acc[i][j][3]);
        *(ushort4*)(vt + (size_t)n * SS + s) = o4;
      }
    return;
  }

  u16* out = (n0t < 1024) ? Q : K;
  const int n0 = n0t & 1023;
#pragma unroll
  for (int i = 0; i < 4; ++i)
#pragma unroll
    for (int j = 0; j < 4; ++j)
#pragma unroll
      for (int r = 0; r < 4; ++r) {
        const int m = m0 + wm * 64 + i * 16 + (l >> 4) * 4 + r;
        const int n = n0 + wn * 64 + j * 16 + (l & 15);
        out[(size_t)m * DD + n] = f2bf(acc[i][j][r]);
      }
}

// ---- kernel 2: Scb = bf16(Q K^T / 32), lower-triangular blocks only,
//      triangular-packed grid: blockIdx.x in [0,136) decodes to (mb,nb) ----
__global__ __launch_bounds__(256, 3) void scores_gemm(const u16* __restrict__ Q,
                                                      const u16* __restrict__ Kt,
                                                      u16* __restrict__ Scb) {
  const int b = blockIdx.z;
  const int tcode = blockIdx.x;  // 0..135
  int mb = (int)((sqrtf(8.0f * (float)tcode + 1.0f) - 1.0f) * 0.5f);
  while ((mb + 1) * (mb + 2) / 2 <= tcode) ++mb;  // fixup fp error
  while (mb * (mb + 1) / 2 > tcode) --mb;
  const int nb = tcode - mb * (mb + 1) / 2;
  const int m0 = mb * 128, n0 = nb * 128;

  floatx4 acc[4][4];
  gemm_core_128(Q + (size_t)b * SS * DD, Kt + (size_t)b * SS * DD, DD, DD, m0, n0, DD, acc);

  u16* out = Scb + (size_t)b * SS * SS;
  const int t = threadIdx.x, w = t >> 6, l = t & 63;
  const int wm = w >> 1, wn = w & 1;
#pragma unroll
  for (int i = 0; i < 4; ++i)
#pragma unroll
    for (int j = 0; j < 4; ++j)
#pragma unroll
      for (int r = 0; r < 4; ++r) {
        const int m = m0 + wm * 64 + i * 16 + (l >> 4) * 4 + r;
        const int n = n0 + wn * 64 + j * 16 + (l & 15);
        out[(size_t)m * SS + n] = f2bf(acc[i][j][r] * 0.03125f);  // 1/sqrt(1024)
      }
}

// ---- kernel 3: causal row softmax, one WAVE per row, register-cached.
//      bf16 in (Scb), bf16 out (P); single global read; no LDS/barriers. ----
__global__ __launch_bounds__(256) void softmax_causal(const u16* __restrict__ Scb,
                                                      u16* __restrict__ P) {
  const int row = blockIdx.x * 4 + (threadIdx.x >> 6);  // b*2048 + i
  const int l = threadIdx.x & 63;
  const int b = row >> 11, i = row & 2047;
  const u16* s = Scb + (size_t)b * SS * SS + (size_t)i * SS;
  u16* p = P + (size_t)b * SS * SS + (size_t)i * SS;
  const int n = i + 1;                      // valid columns [0, n)
  const int jend = (i + 128) & ~127;        // pv reads cols [0, jend)
  const int nc = (jend + 511) >> 9;         // 512-col chunks (1..4)

  float v[4][8];
  float mx = -INFINITY;
#pragma unroll
  for (int c = 0; c < 4; ++c) {
    if (c < nc) {
      const int col = c * 512 + l * 8;
      uint4 raw = *(const uint4*)(s + col);
      v[c][0] = bflo2f(raw.x); v[c][1] = bfhi2f(raw.x);
      v[c][2] = bflo2f(raw.y); v[c][3] = bfhi2f(raw.y);
      v[c][4] = bflo2f(raw.z); v[c][5] = bfhi2f(raw.z);
      v[c][6] = bflo2f(raw.w); v[c][7] = bfhi2f(raw.w);
#pragma unroll
      for (int e = 0; e < 8; ++e) {
        v[c][e] = (col + e < n) ? v[c][e] : -INFINITY;
        mx = fmaxf(mx, v[c][e]);
      }
    }
  }
#pragma unroll
  for (int o = 32; o > 0; o >>= 1) mx = fmaxf(mx, __shfl_xor(mx, o, 64));

  float sum = 0.f;
#pragma unroll
  for (int c = 0; c < 4; ++c) {
    if (c < nc) {
#pragma unroll
      for (int e = 0; e < 8; ++e) {
        v[c][e] = __expf(v[c][e] - mx);  // exp(-inf)=0 for masked cols
        sum += v[c][e];
      }
    }
  }
#pragma unroll
  for (int o = 32; o > 0; o >>= 1) sum += __shfl_xor(sum, o, 64);
  const float inv = 1.0f / sum;

#pragma unroll
  for (int c = 0; c < 4; ++c) {
    if (c < nc) {
      const int col = c * 512 + l * 8;
      if (col < jend) {  // jend % 128 == 0 -> whole 8-granule in or out
        uint4 o4;
        o4.x = (uint32_t)f2bf(v[c][0] * inv) | ((uint32_t)f2bf(v[c][1] * inv) << 16);
        o4.y = (uint32_t)f2bf(v[c][2] * inv) | ((uint32_t)f2bf(v[c][3] * inv) << 16);
        o4.z = (uint32_t)f2bf(v[c][4] * inv) | ((uint32_t)f2bf(v[c][5] * inv) << 16);
        o4.w = (uint32_t)f2bf(v[c][6] * inv) | ((uint32_t)f2bf(v[c][7] * inv) << 16);
        *(uint4*)(p + col) = o4;
      }
    }
  }
}

// ---- kernel 4: O = P V (causal K-range), fp32 out.
//      Grid dim3(512): stride-256 long/short pairing. Under breadth-first
//      dispatch, CU c receives blocks c and c+256; we map x<256 to the 256
//      LONG tiles (mb=15..8, work 16..9 units) and x>=256 to the matching
//      SHORT tiles (mb=0..7, work 1..8), same j -> per-CU work = 17 units
//      uniformly (ideal makespan ~21us vs ~40us tail). Long blocks dispatch
//      first, preserving longest-first backfill. Worst case (wrong CP model)
//      degenerates to previous behavior. ----
__global__ __launch_bounds__(256, 3) void pv_gemm(const u16* __restrict__ P,
                                                  const u16* __restrict__ Vt,
                                                  float* __restrict__ out) {
  const int x = blockIdx.x;      // 0..511
  const int j = x & 255;
  const int mb = (x < 256) ? (15 - (j >> 5)) : (j >> 5);
  const int b  = (j >> 3) & 3;
  const int nb = j & 7;
  const int m0 = mb * 128, n0 = nb * 128;
  floatx4 acc[4][4];
  // rows m0..m0+127 only attend to keys k < m0+128
  gemm_core_128(P + (size_t)b * SS * SS, Vt + (size_t)b * DD * SS, SS, SS, m0, n0, m0 + 128, acc);

  float* o = out + (size_t)b * SS * DD;
  const int t = threadIdx.x, w = t >> 6, l = t & 63;
  const int wm = w >> 1, wn = w & 1;
#pragma unroll
  for (int i = 0; i < 4; ++i)
#pragma unroll
    for (int j2 = 0; j2 < 4; ++j2)
#pragma unroll
      for (int r = 0; r < 4; ++r) {
        const int m = m0 + wm * 64 + i * 16 + (l >> 4) * 4 + r;
        const int n = n0 + wn * 64 + j2 * 16 + (l & 15);
        o[(size_t)m * DD + n] = acc[i][j2][r];
      }
}

extern "C" void kernel_launch(void* const* d_in, const int* in_sizes, int n_in,
                              void* d_out, int out_size, void* d_ws, size_t ws_size,
                              hipStream_t stream) {
  const float* x  = (const float*)d_in[0];
  const float* WQ = (const float*)d_in[1];
  const float* WK = (const float*)d_in[2];
  const float* WV = (const float*)d_in[3];
  float* out = (float*)d_out;

  // workspace carve (bytes): Wt 6M | xb 16M | Q 16M | K 16M | Vt 16M | P 32M | Scb 32M
  char* ws = (char*)d_ws;
  const size_t WT_OFF = 0;
  const size_t XB_OFF = WT_OFF + (size_t)3072 * 1024 * 2;
  const size_t Q_OFF  = XB_OFF + (size_t)BB * SS * DD * 2;
  const size_t K_OFF  = Q_OFF + (size_t)BB * SS * DD * 2;
  const size_t VT_OFF = K_OFF + (size_t)BB * SS * DD * 2;
  const size_t P_OFF  = VT_OFF + (size_t)BB * SS * DD * 2;
  const size_t SC_OFF = P_OFF + (size_t)BB * SS * SS * 2;
  u16* Wt  = (u16*)(ws + WT_OFF);
  u16* xb  = (u16*)(ws + XB_OFF);
  u16* Q   = (u16*)(ws + Q_OFF);
  u16* Kb  = (u16*)(ws + K_OFF);
  u16* Vt  = (u16*)(ws + VT_OFF);
  u16* P   = (u16*)(ws + P_OFF);
  u16* Scb = (u16*)(ws + SC_OFF);

  hipLaunchKernelGGL(prep, dim3(8960), dim3(256), 0, stream, x, WQ, WK, WV, xb, Wt);
  hipLaunchKernelGGL(qkv_gemm, dim3(64, 24), dim3(256), 0, stream, xb, Wt, Q, Kb, Vt);
  hipLaunchKernelGGL(scores_gemm, dim3(136, 1, 4), dim3(256), 0, stream, Q, Kb, Scb);
  hipLaunchKernelGGL(softmax_causal, dim3(2048), dim3(256), 0, stream, Scb, P);
  hipLaunchKernelGGL(pv_gemm, dim3(512), dim3(256), 0, stream, P, Vt, out);
}